// Round 12
// baseline (490.899 us; speedup 1.0000x reference)
//
#include <hip/hip_runtime.h>

#define N_NODES 100000
#define N_EDGES 1000000
#define EPS 1e-5f
#define SLOPE 0.01f
#define NBUCK 391    // ceil(N/256) buckets of 256 consecutive nodes
#define BCAP 3072    // records/bucket: Poisson(2560) + 10 sigma

// ---------------------------------------------------------------------------
// ws layout:
//   Pb   : NBUCK*BCAP*32 B (38.4 MB)  {float4 ef; float4 {src,..}} bucket-major
//   dl   : NBUCK*BCAP*2 B  (2.4 MB)   u16 local dst (dst & 255), bucket-major
//   bcur : NBUCK ints  [zeroed]       bucket append cursors
//   stats: 32 floats   [zeroed]       sum[16], sumsq[16]
// Measured design rules:
//   r1/r3 : node-granular CSR scatter = 64 B/edge HBM write (100k live write
//           cursors defeat L2 merge) at only 1.3 TB/s (poor row locality).
//   r4-r7 : 1 thr/node gather + x4 ILP unroll is the right gather shape.
//   r8/r9 : grid.sync fusion is NOT coherence-safe on 8-XCD MI355X.
//   r10   : nt stores/L2-bypass regress; plain cached stores optimal.
//   r11   : ~16 us/dispatch fixed gap -> minimize dispatches.
//   r12   : bucket-append (391 live tails, L2-merged, row-local) + in-LDS
//           local CSR per bucket. count/scan1/scatter -> ONE bin pass;
//           6 dispatches -> 4.
// ---------------------------------------------------------------------------

// Kernel 1: bin edges into bucket-major staging (one sequential edge pass).
__global__ __launch_bounds__(256) void bin_kernel(
    const float* __restrict__ efeat,
    const int* __restrict__ edge_index,
    int* __restrict__ bcur,
    float4* __restrict__ Pb,
    unsigned short* __restrict__ dl)
{
    int eid = blockIdx.x * 256 + threadIdx.x;
    if (eid >= N_EDGES) return;
    int src = edge_index[eid];
    int dst = edge_index[N_EDGES + eid];
    float4 ef = *(const float4*)(efeat + (size_t)eid * 4);
    int b = dst >> 8;
    int slot = atomicAdd(bcur + b, 1);
    if (slot < BCAP) {                          // 10-sigma margin; never trips
        size_t rec = (size_t)b * BCAP + slot;
        Pb[2 * rec]     = ef;
        Pb[2 * rec + 1] = make_float4(__int_as_float(src), 0.f, 0.f, 0.f);
        dl[rec] = (unsigned short)(dst & 255);
    }
}

// ---------------------------------------------------------------------------
// Kernel 2: per-bucket fused CSR-build + gather + node transform.
// Block b owns nodes [b*256, b*256+256). Local CSR built in LDS:
//   A) stream dl -> LDS copy + LDS histogram
//   B) LDS exclusive scan (start per node)
//   C) LDS rank -> perm (record index per CSR slot)
//   D) per-thread gather with x4 ILP unroll; record reads are random but
//      confined to this bucket's 96 KB region (L2-hot from phase A).
// Then contraction + root + bias + out write + batch-stat reduction (r7).
// ---------------------------------------------------------------------------
__global__ __launch_bounds__(256) void gather_bucket_kernel(
    const float* __restrict__ v,
    const float4* __restrict__ Pb,
    const unsigned short* __restrict__ dl,
    const int* __restrict__ bcur,
    const float* __restrict__ enet_w,
    const float* __restrict__ enet_b,
    const float* __restrict__ root,
    const float* __restrict__ bias,
    float* __restrict__ out,
    float* __restrict__ stats)
{
    __shared__ unsigned short s_dl[BCAP];     // 6 KB
    __shared__ unsigned short s_perm[BCAP];   // 6 KB
    __shared__ int s_hist[256];
    __shared__ int s_sc[256];
    __shared__ int s_cur[256];
    __shared__ float s_part[4][32];

    const int b = blockIdx.x;
    const int tid = threadIdx.x;
    const int cnt = min(bcur[b], BCAP);
    const size_t base = (size_t)b * BCAP;

    // A) load local dsts + histogram
    s_hist[tid] = 0;
    __syncthreads();
    for (int i = tid; i < cnt; i += 256) {
        unsigned short d = dl[base + i];
        s_dl[i] = d;
        atomicAdd(&s_hist[d], 1);
    }
    __syncthreads();

    // B) exclusive scan of s_hist
    int deg = s_hist[tid];
    s_sc[tid] = deg;
    __syncthreads();
    #pragma unroll
    for (int off = 1; off < 256; off <<= 1) {
        int t = (tid >= off) ? s_sc[tid - off] : 0;
        __syncthreads();
        s_sc[tid] += t;
        __syncthreads();
    }
    int start = s_sc[tid] - deg;
    s_cur[tid] = start;
    __syncthreads();

    // C) rank: perm[csr_slot] = record index
    for (int i = tid; i < cnt; i += 256) {
        int slot = atomicAdd(&s_cur[s_dl[i]], 1);
        s_perm[slot] = (unsigned short)i;
    }
    __syncthreads();

    // D) gather with x4 ILP unroll (r7 body; record reads L2-local)
    int n = b * 256 + tid;
    bool active = (n < N_NODES);

    float acc[80];
    #pragma unroll
    for (int i = 0; i < 80; ++i) acc[i] = 0.0f;

    const float4* pp = Pb + 2 * base;
    int j = 0;
    for (; j + 4 <= deg; j += 4) {
        int r0 = s_perm[start + j + 0];
        int r1 = s_perm[start + j + 1];
        int r2 = s_perm[start + j + 2];
        int r3 = s_perm[start + j + 3];
        float4 ef0 = pp[2*r0], sp0 = pp[2*r0+1];
        float4 ef1 = pp[2*r1], sp1 = pp[2*r1+1];
        float4 ef2 = pp[2*r2], sp2 = pp[2*r2+1];
        float4 ef3 = pp[2*r3], sp3 = pp[2*r3+1];
        int s0 = __float_as_int(sp0.x);
        int s1 = __float_as_int(sp1.x);
        int s2 = __float_as_int(sp2.x);
        int s3 = __float_as_int(sp3.x);
        const float4* vr0 = (const float4*)(v + (size_t)s0 * 16);
        const float4* vr1 = (const float4*)(v + (size_t)s1 * 16);
        const float4* vr2 = (const float4*)(v + (size_t)s2 * 16);
        const float4* vr3 = (const float4*)(v + (size_t)s3 * 16);
        #pragma unroll
        for (int i = 0; i < 4; ++i) {
            float4 a = vr0[i], bb = vr1[i], c = vr2[i], d = vr3[i];
            acc[     i*4+0] += (a.x + bb.x) + (c.x + d.x);
            acc[     i*4+1] += (a.y + bb.y) + (c.y + d.y);
            acc[     i*4+2] += (a.z + bb.z) + (c.z + d.z);
            acc[     i*4+3] += (a.w + bb.w) + (c.w + d.w);
            acc[16 + i*4+0] = fmaf(ef0.x, a.x, fmaf(ef1.x, bb.x,
                              fmaf(ef2.x, c.x, fmaf(ef3.x, d.x, acc[16 + i*4+0]))));
            acc[16 + i*4+1] = fmaf(ef0.x, a.y, fmaf(ef1.x, bb.y,
                              fmaf(ef2.x, c.y, fmaf(ef3.x, d.y, acc[16 + i*4+1]))));
            acc[16 + i*4+2] = fmaf(ef0.x, a.z, fmaf(ef1.x, bb.z,
                              fmaf(ef2.x, c.z, fmaf(ef3.x, d.z, acc[16 + i*4+2]))));
            acc[16 + i*4+3] = fmaf(ef0.x, a.w, fmaf(ef1.x, bb.w,
                              fmaf(ef2.x, c.w, fmaf(ef3.x, d.w, acc[16 + i*4+3]))));
            acc[32 + i*4+0] = fmaf(ef0.y, a.x, fmaf(ef1.y, bb.x,
                              fmaf(ef2.y, c.x, fmaf(ef3.y, d.x, acc[32 + i*4+0]))));
            acc[32 + i*4+1] = fmaf(ef0.y, a.y, fmaf(ef1.y, bb.y,
                              fmaf(ef2.y, c.y, fmaf(ef3.y, d.y, acc[32 + i*4+1]))));
            acc[32 + i*4+2] = fmaf(ef0.y, a.z, fmaf(ef1.y, bb.z,
                              fmaf(ef2.y, c.z, fmaf(ef3.y, d.z, acc[32 + i*4+2]))));
            acc[32 + i*4+3] = fmaf(ef0.y, a.w, fmaf(ef1.y, bb.w,
                              fmaf(ef2.y, c.w, fmaf(ef3.y, d.w, acc[32 + i*4+3]))));
            acc[48 + i*4+0] = fmaf(ef0.z, a.x, fmaf(ef1.z, bb.x,
                              fmaf(ef2.z, c.x, fmaf(ef3.z, d.x, acc[48 + i*4+0]))));
            acc[48 + i*4+1] = fmaf(ef0.z, a.y, fmaf(ef1.z, bb.y,
                              fmaf(ef2.z, c.y, fmaf(ef3.z, d.y, acc[48 + i*4+1]))));
            acc[48 + i*4+2] = fmaf(ef0.z, a.z, fmaf(ef1.z, bb.z,
                              fmaf(ef2.z, c.z, fmaf(ef3.z, d.z, acc[48 + i*4+2]))));
            acc[48 + i*4+3] = fmaf(ef0.z, a.w, fmaf(ef1.z, bb.w,
                              fmaf(ef2.z, c.w, fmaf(ef3.z, d.w, acc[48 + i*4+3]))));
            acc[64 + i*4+0] = fmaf(ef0.w, a.x, fmaf(ef1.w, bb.x,
                              fmaf(ef2.w, c.x, fmaf(ef3.w, d.x, acc[64 + i*4+0]))));
            acc[64 + i*4+1] = fmaf(ef0.w, a.y, fmaf(ef1.w, bb.y,
                              fmaf(ef2.w, c.y, fmaf(ef3.w, d.y, acc[64 + i*4+1]))));
            acc[64 + i*4+2] = fmaf(ef0.w, a.z, fmaf(ef1.w, bb.z,
                              fmaf(ef2.w, c.z, fmaf(ef3.w, d.z, acc[64 + i*4+2]))));
            acc[64 + i*4+3] = fmaf(ef0.w, a.w, fmaf(ef1.w, bb.w,
                              fmaf(ef2.w, c.w, fmaf(ef3.w, d.w, acc[64 + i*4+3]))));
        }
    }
    for (; j < deg; ++j) {
        int r0 = s_perm[start + j];
        float4 ef = pp[2*r0];
        float4 sp = pp[2*r0+1];
        int src = __float_as_int(sp.x);
        const float4* vr = (const float4*)(v + (size_t)src * 16);
        #pragma unroll
        for (int i = 0; i < 4; ++i) {
            float4 a = vr[i];
            acc[     i*4+0] += a.x;
            acc[     i*4+1] += a.y;
            acc[     i*4+2] += a.z;
            acc[     i*4+3] += a.w;
            acc[16 + i*4+0] = fmaf(ef.x, a.x, acc[16 + i*4+0]);
            acc[16 + i*4+1] = fmaf(ef.x, a.y, acc[16 + i*4+1]);
            acc[16 + i*4+2] = fmaf(ef.x, a.z, acc[16 + i*4+2]);
            acc[16 + i*4+3] = fmaf(ef.x, a.w, acc[16 + i*4+3]);
            acc[32 + i*4+0] = fmaf(ef.y, a.x, acc[32 + i*4+0]);
            acc[32 + i*4+1] = fmaf(ef.y, a.y, acc[32 + i*4+1]);
            acc[32 + i*4+2] = fmaf(ef.y, a.z, acc[32 + i*4+2]);
            acc[32 + i*4+3] = fmaf(ef.y, a.w, acc[32 + i*4+3]);
            acc[48 + i*4+0] = fmaf(ef.z, a.x, acc[48 + i*4+0]);
            acc[48 + i*4+1] = fmaf(ef.z, a.y, acc[48 + i*4+1]);
            acc[48 + i*4+2] = fmaf(ef.z, a.z, acc[48 + i*4+2]);
            acc[48 + i*4+3] = fmaf(ef.z, a.w, acc[48 + i*4+3]);
            acc[64 + i*4+0] = fmaf(ef.w, a.x, acc[64 + i*4+0]);
            acc[64 + i*4+1] = fmaf(ef.w, a.y, acc[64 + i*4+1]);
            acc[64 + i*4+2] = fmaf(ef.w, a.z, acc[64 + i*4+2]);
            acc[64 + i*4+3] = fmaf(ef.w, a.w, acc[64 + i*4+3]);
        }
    }

    float val[16];
    if (active) {
        float vn[16];
        #pragma unroll
        for (int i = 0; i < 4; ++i) {
            float4 tv = *(const float4*)(v + (size_t)n * 16 + i * 4);
            vn[4*i+0] = tv.x; vn[4*i+1] = tv.y;
            vn[4*i+2] = tv.z; vn[4*i+3] = tv.w;
        }
        float scale = 1.0f / fmaxf((float)deg, 1.0f);
        #pragma unroll
        for (int o = 0; o < 16; ++o) {
            float a = 0.0f;
            #pragma unroll
            for (int i = 0; i < 16; ++i) {
                a = fmaf(acc[i], enet_b[i * 16 + o], a);           // S0 * B
                #pragma unroll
                for (int k = 0; k < 4; ++k)
                    a = fmaf(acc[16 + k * 16 + i],
                             enet_w[(i * 16 + o) * 4 + k], a);     // Sk * Wk
            }
            a = fmaf(a, scale, bias[o]);
            #pragma unroll
            for (int i = 0; i < 16; ++i)
                a = fmaf(vn[i], root[i * 16 + o], a);
            val[o] = a;
        }
        #pragma unroll
        for (int i = 0; i < 4; ++i)
            *(float4*)(out + (size_t)n * 16 + i * 4) =
                make_float4(val[4*i+0], val[4*i+1], val[4*i+2], val[4*i+3]);
    } else {
        #pragma unroll
        for (int o = 0; o < 16; ++o) val[o] = 0.0f;
    }

    // batch-stat reduction: wave butterfly -> LDS -> device atomic
    float ssum[16], ssq[16];
    #pragma unroll
    for (int o = 0; o < 16; ++o) {
        float a = val[o];
        float bsq = a * a;
        #pragma unroll
        for (int m = 1; m < 64; m <<= 1) {
            a += __shfl_xor(a, m, 64);
            bsq += __shfl_xor(bsq, m, 64);
        }
        ssum[o] = a; ssq[o] = bsq;
    }
    int wave = tid >> 6;
    int lane = tid & 63;
    if (lane == 0) {
        #pragma unroll
        for (int o = 0; o < 16; ++o) {
            s_part[wave][o]      = ssum[o];
            s_part[wave][16 + o] = ssq[o];
        }
    }
    __syncthreads();
    if (tid < 32) {
        float t = s_part[0][tid] + s_part[1][tid] +
                  s_part[2][tid] + s_part[3][tid];
        unsafeAtomicAdd(stats + tid, t);
    }
}

// Kernel 3: BatchNorm (batch stats) + LeakyReLU, in place, float4-vectorized.
__global__ __launch_bounds__(256) void final_kernel(
    float* __restrict__ out,
    const float* __restrict__ stats,
    const float* __restrict__ gamma,
    const float* __restrict__ beta)
{
    int idx = blockIdx.x * 256 + threadIdx.x;      // float4 index
    if (idx >= N_NODES * 4) return;
    int o0 = (idx & 3) << 2;
    const float invN = 1.0f / (float)N_NODES;
    float4 x = *((const float4*)out + idx);
    float xs[4] = {x.x, x.y, x.z, x.w};
    float r[4];
    #pragma unroll
    for (int u = 0; u < 4; ++u) {
        int o = o0 + u;
        float mu = stats[o] * invN;
        float var = fmaxf(stats[16 + o] * invN - mu * mu, 0.0f);
        float y = fmaf(gamma[o] * (xs[u] - mu), rsqrtf(var + EPS), beta[o]);
        r[u] = (y >= 0.0f) ? y : SLOPE * y;
    }
    *((float4*)out + idx) = make_float4(r[0], r[1], r[2], r[3]);
}

extern "C" void kernel_launch(void* const* d_in, const int* in_sizes, int n_in,
                              void* d_out, int out_size, void* d_ws, size_t ws_size,
                              hipStream_t stream)
{
    const float* v = (const float*)d_in[0];
    const float* e = (const float*)d_in[1];
    const int* edge_index = (const int*)d_in[2];
    const float* enet_w = (const float*)d_in[3];
    const float* enet_b = (const float*)d_in[4];
    const float* root = (const float*)d_in[5];
    const float* bias = (const float*)d_in[6];
    const float* gamma = (const float*)d_in[7];
    const float* beta = (const float*)d_in[8];
    float* out = (float*)d_out;

    char* ws = (char*)d_ws;
    float4*         Pb    = (float4*)ws;          ws += (size_t)NBUCK * BCAP * 32;
    unsigned short* dl    = (unsigned short*)ws;  ws += (size_t)NBUCK * BCAP * 2;
    int*            bcur  = (int*)ws;             ws += (size_t)NBUCK * 4;
    float*          stats = (float*)ws;

    // zero bcur + stats (contiguous, tiny)
    hipMemsetAsync(bcur, 0, (size_t)NBUCK * 4 + 32 * 4, stream);

    bin_kernel<<<(N_EDGES + 255) / 256, 256, 0, stream>>>(
        e, edge_index, bcur, Pb, dl);
    gather_bucket_kernel<<<NBUCK, 256, 0, stream>>>(
        v, Pb, dl, bcur, enet_w, enet_b, root, bias, out, stats);
    final_kernel<<<(N_NODES * 4 + 255) / 256, 256, 0, stream>>>(
        out, stats, gamma, beta);
}

// Round 13
// 171.229 us; speedup vs baseline: 2.8669x; 2.8669x over previous
//
#include <hip/hip_runtime.h>

#define N_NODES 100000
#define N_EDGES 1000000
#define EPS 1e-5f
#define SLOPE 0.01f
#define NBUCK 391    // ceil(N/256) buckets of 256 consecutive nodes
#define BCAP 3072    // records/bucket: Poisson(2560) + 10 sigma
#define EPB 2560     // edges per bin block (10 iters of 256)
#define NBINB 391    // ceil(N_EDGES / EPB)

// ---------------------------------------------------------------------------
// ws layout:
//   Pb   : NBUCK*BCAP*32 B (38.4 MB)  {float4 ef; float4 {src,..}} bucket-major
//   dl   : NBUCK*BCAP*2 B  (2.4 MB)   u16 local dst (dst & 255), bucket-major
//   bcur : NBUCK ints  [zeroed]       bucket append cursors
//   stats: 32 floats   [zeroed]       sum[16], sumsq[16]
// Measured design rules:
//   r1/r3 : node-granular CSR scatter = 64 B/edge HBM write at 1.3 TB/s.
//   r4-r7 : 1 thr/node gather + x4 ILP unroll is the right gather shape.
//   r8/r9 : grid.sync fusion is NOT coherence-safe on 8-XCD MI355X.
//   r10   : nt stores/L2-bypass regress; plain cached stores optimal.
//   r11   : ~16 us/dispatch fixed gap -> minimize dispatches.
//   r12   : per-edge global atomics on 391 bucket cursors = 352 us of pure
//           serialization (VALU 0.16%, HBM 3%): 2560 RMWs/address in series.
//   r13   : block-aggregated reservation — LDS hist, ONE global atomic per
//           (block, bucket), LDS cursors for slot assignment. ~325 RMWs per
//           address, each reserving ~6.5 slots; block's records contiguous.
// ---------------------------------------------------------------------------

// Kernel 1: bin edges into bucket-major staging, block-aggregated atomics.
__global__ __launch_bounds__(256) void bin_kernel(
    const float* __restrict__ efeat,
    const int* __restrict__ edge_index,
    int* __restrict__ bcur,
    float4* __restrict__ Pb,
    unsigned short* __restrict__ dl)
{
    __shared__ int s_hist[NBUCK];
    __shared__ int s_base[NBUCK];

    const int tid = threadIdx.x;
    const int e0 = blockIdx.x * EPB;
    const int e1 = min(e0 + EPB, N_EDGES);

    // pass 1: LDS histogram of this chunk's buckets
    for (int i = tid; i < NBUCK; i += 256) s_hist[i] = 0;
    __syncthreads();
    for (int eid = e0 + tid; eid < e1; eid += 256) {
        int dst = edge_index[N_EDGES + eid];
        atomicAdd(&s_hist[dst >> 8], 1);
    }
    __syncthreads();

    // pass 2: one global reservation per non-empty bucket
    for (int b = tid; b < NBUCK; b += 256) {
        int c = s_hist[b];
        s_base[b] = c ? atomicAdd(bcur + b, c) : 0;
    }
    __syncthreads();
    // reuse s_hist as local slot cursor
    for (int i = tid; i < NBUCK; i += 256) s_hist[i] = 0;
    __syncthreads();

    // pass 3: write records into reserved contiguous ranges
    for (int eid = e0 + tid; eid < e1; eid += 256) {
        int src = edge_index[eid];
        int dst = edge_index[N_EDGES + eid];
        float4 ef = *(const float4*)(efeat + (size_t)eid * 4);
        int b = dst >> 8;
        int slot = s_base[b] + atomicAdd(&s_hist[b], 1);
        if (slot < BCAP) {                      // 10-sigma margin; never trips
            size_t rec = (size_t)b * BCAP + slot;
            Pb[2 * rec]     = ef;
            Pb[2 * rec + 1] = make_float4(__int_as_float(src), 0.f, 0.f, 0.f);
            dl[rec] = (unsigned short)(dst & 255);
        }
    }
}

// ---------------------------------------------------------------------------
// Kernel 2: per-bucket fused CSR-build + gather + node transform (r12 body,
// unchanged — passed correctness). Block b owns nodes [b*256, b*256+256).
// ---------------------------------------------------------------------------
__global__ __launch_bounds__(256) void gather_bucket_kernel(
    const float* __restrict__ v,
    const float4* __restrict__ Pb,
    const unsigned short* __restrict__ dl,
    const int* __restrict__ bcur,
    const float* __restrict__ enet_w,
    const float* __restrict__ enet_b,
    const float* __restrict__ root,
    const float* __restrict__ bias,
    float* __restrict__ out,
    float* __restrict__ stats)
{
    __shared__ unsigned short s_dl[BCAP];     // 6 KB
    __shared__ unsigned short s_perm[BCAP];   // 6 KB
    __shared__ int s_hist[256];
    __shared__ int s_sc[256];
    __shared__ int s_cur[256];
    __shared__ float s_part[4][32];

    const int b = blockIdx.x;
    const int tid = threadIdx.x;
    const int cnt = min(bcur[b], BCAP);
    const size_t base = (size_t)b * BCAP;

    // A) load local dsts + histogram
    s_hist[tid] = 0;
    __syncthreads();
    for (int i = tid; i < cnt; i += 256) {
        unsigned short d = dl[base + i];
        s_dl[i] = d;
        atomicAdd(&s_hist[d], 1);
    }
    __syncthreads();

    // B) exclusive scan of s_hist
    int deg = s_hist[tid];
    s_sc[tid] = deg;
    __syncthreads();
    #pragma unroll
    for (int off = 1; off < 256; off <<= 1) {
        int t = (tid >= off) ? s_sc[tid - off] : 0;
        __syncthreads();
        s_sc[tid] += t;
        __syncthreads();
    }
    int start = s_sc[tid] - deg;
    s_cur[tid] = start;
    __syncthreads();

    // C) rank: perm[csr_slot] = record index
    for (int i = tid; i < cnt; i += 256) {
        int slot = atomicAdd(&s_cur[s_dl[i]], 1);
        s_perm[slot] = (unsigned short)i;
    }
    __syncthreads();

    // D) gather with x4 ILP unroll (r7 body; record reads L2-local)
    int n = b * 256 + tid;
    bool active = (n < N_NODES);

    float acc[80];
    #pragma unroll
    for (int i = 0; i < 80; ++i) acc[i] = 0.0f;

    const float4* pp = Pb + 2 * base;
    int j = 0;
    for (; j + 4 <= deg; j += 4) {
        int r0 = s_perm[start + j + 0];
        int r1 = s_perm[start + j + 1];
        int r2 = s_perm[start + j + 2];
        int r3 = s_perm[start + j + 3];
        float4 ef0 = pp[2*r0], sp0 = pp[2*r0+1];
        float4 ef1 = pp[2*r1], sp1 = pp[2*r1+1];
        float4 ef2 = pp[2*r2], sp2 = pp[2*r2+1];
        float4 ef3 = pp[2*r3], sp3 = pp[2*r3+1];
        int s0 = __float_as_int(sp0.x);
        int s1 = __float_as_int(sp1.x);
        int s2 = __float_as_int(sp2.x);
        int s3 = __float_as_int(sp3.x);
        const float4* vr0 = (const float4*)(v + (size_t)s0 * 16);
        const float4* vr1 = (const float4*)(v + (size_t)s1 * 16);
        const float4* vr2 = (const float4*)(v + (size_t)s2 * 16);
        const float4* vr3 = (const float4*)(v + (size_t)s3 * 16);
        #pragma unroll
        for (int i = 0; i < 4; ++i) {
            float4 a = vr0[i], bb = vr1[i], c = vr2[i], d = vr3[i];
            acc[     i*4+0] += (a.x + bb.x) + (c.x + d.x);
            acc[     i*4+1] += (a.y + bb.y) + (c.y + d.y);
            acc[     i*4+2] += (a.z + bb.z) + (c.z + d.z);
            acc[     i*4+3] += (a.w + bb.w) + (c.w + d.w);
            acc[16 + i*4+0] = fmaf(ef0.x, a.x, fmaf(ef1.x, bb.x,
                              fmaf(ef2.x, c.x, fmaf(ef3.x, d.x, acc[16 + i*4+0]))));
            acc[16 + i*4+1] = fmaf(ef0.x, a.y, fmaf(ef1.x, bb.y,
                              fmaf(ef2.x, c.y, fmaf(ef3.x, d.y, acc[16 + i*4+1]))));
            acc[16 + i*4+2] = fmaf(ef0.x, a.z, fmaf(ef1.x, bb.z,
                              fmaf(ef2.x, c.z, fmaf(ef3.x, d.z, acc[16 + i*4+2]))));
            acc[16 + i*4+3] = fmaf(ef0.x, a.w, fmaf(ef1.x, bb.w,
                              fmaf(ef2.x, c.w, fmaf(ef3.x, d.w, acc[16 + i*4+3]))));
            acc[32 + i*4+0] = fmaf(ef0.y, a.x, fmaf(ef1.y, bb.x,
                              fmaf(ef2.y, c.x, fmaf(ef3.y, d.x, acc[32 + i*4+0]))));
            acc[32 + i*4+1] = fmaf(ef0.y, a.y, fmaf(ef1.y, bb.y,
                              fmaf(ef2.y, c.y, fmaf(ef3.y, d.y, acc[32 + i*4+1]))));
            acc[32 + i*4+2] = fmaf(ef0.y, a.z, fmaf(ef1.y, bb.z,
                              fmaf(ef2.y, c.z, fmaf(ef3.y, d.z, acc[32 + i*4+2]))));
            acc[32 + i*4+3] = fmaf(ef0.y, a.w, fmaf(ef1.y, bb.w,
                              fmaf(ef2.y, c.w, fmaf(ef3.y, d.w, acc[32 + i*4+3]))));
            acc[48 + i*4+0] = fmaf(ef0.z, a.x, fmaf(ef1.z, bb.x,
                              fmaf(ef2.z, c.x, fmaf(ef3.z, d.x, acc[48 + i*4+0]))));
            acc[48 + i*4+1] = fmaf(ef0.z, a.y, fmaf(ef1.z, bb.y,
                              fmaf(ef2.z, c.y, fmaf(ef3.z, d.y, acc[48 + i*4+1]))));
            acc[48 + i*4+2] = fmaf(ef0.z, a.z, fmaf(ef1.z, bb.z,
                              fmaf(ef2.z, c.z, fmaf(ef3.z, d.z, acc[48 + i*4+2]))));
            acc[48 + i*4+3] = fmaf(ef0.z, a.w, fmaf(ef1.z, bb.w,
                              fmaf(ef2.z, c.w, fmaf(ef3.z, d.w, acc[48 + i*4+3]))));
            acc[64 + i*4+0] = fmaf(ef0.w, a.x, fmaf(ef1.w, bb.x,
                              fmaf(ef2.w, c.x, fmaf(ef3.w, d.x, acc[64 + i*4+0]))));
            acc[64 + i*4+1] = fmaf(ef0.w, a.y, fmaf(ef1.w, bb.y,
                              fmaf(ef2.w, c.y, fmaf(ef3.w, d.y, acc[64 + i*4+1]))));
            acc[64 + i*4+2] = fmaf(ef0.w, a.z, fmaf(ef1.w, bb.z,
                              fmaf(ef2.w, c.z, fmaf(ef3.w, d.z, acc[64 + i*4+2]))));
            acc[64 + i*4+3] = fmaf(ef0.w, a.w, fmaf(ef1.w, bb.w,
                              fmaf(ef2.w, c.w, fmaf(ef3.w, d.w, acc[64 + i*4+3]))));
        }
    }
    for (; j < deg; ++j) {
        int r0 = s_perm[start + j];
        float4 ef = pp[2*r0];
        float4 sp = pp[2*r0+1];
        int src = __float_as_int(sp.x);
        const float4* vr = (const float4*)(v + (size_t)src * 16);
        #pragma unroll
        for (int i = 0; i < 4; ++i) {
            float4 a = vr[i];
            acc[     i*4+0] += a.x;
            acc[     i*4+1] += a.y;
            acc[     i*4+2] += a.z;
            acc[     i*4+3] += a.w;
            acc[16 + i*4+0] = fmaf(ef.x, a.x, acc[16 + i*4+0]);
            acc[16 + i*4+1] = fmaf(ef.x, a.y, acc[16 + i*4+1]);
            acc[16 + i*4+2] = fmaf(ef.x, a.z, acc[16 + i*4+2]);
            acc[16 + i*4+3] = fmaf(ef.x, a.w, acc[16 + i*4+3]);
            acc[32 + i*4+0] = fmaf(ef.y, a.x, acc[32 + i*4+0]);
            acc[32 + i*4+1] = fmaf(ef.y, a.y, acc[32 + i*4+1]);
            acc[32 + i*4+2] = fmaf(ef.y, a.z, acc[32 + i*4+2]);
            acc[32 + i*4+3] = fmaf(ef.y, a.w, acc[32 + i*4+3]);
            acc[48 + i*4+0] = fmaf(ef.z, a.x, acc[48 + i*4+0]);
            acc[48 + i*4+1] = fmaf(ef.z, a.y, acc[48 + i*4+1]);
            acc[48 + i*4+2] = fmaf(ef.z, a.z, acc[48 + i*4+2]);
            acc[48 + i*4+3] = fmaf(ef.z, a.w, acc[48 + i*4+3]);
            acc[64 + i*4+0] = fmaf(ef.w, a.x, acc[64 + i*4+0]);
            acc[64 + i*4+1] = fmaf(ef.w, a.y, acc[64 + i*4+1]);
            acc[64 + i*4+2] = fmaf(ef.w, a.z, acc[64 + i*4+2]);
            acc[64 + i*4+3] = fmaf(ef.w, a.w, acc[64 + i*4+3]);
        }
    }

    float val[16];
    if (active) {
        float vn[16];
        #pragma unroll
        for (int i = 0; i < 4; ++i) {
            float4 tv = *(const float4*)(v + (size_t)n * 16 + i * 4);
            vn[4*i+0] = tv.x; vn[4*i+1] = tv.y;
            vn[4*i+2] = tv.z; vn[4*i+3] = tv.w;
        }
        float scale = 1.0f / fmaxf((float)deg, 1.0f);
        #pragma unroll
        for (int o = 0; o < 16; ++o) {
            float a = 0.0f;
            #pragma unroll
            for (int i = 0; i < 16; ++i) {
                a = fmaf(acc[i], enet_b[i * 16 + o], a);           // S0 * B
                #pragma unroll
                for (int k = 0; k < 4; ++k)
                    a = fmaf(acc[16 + k * 16 + i],
                             enet_w[(i * 16 + o) * 4 + k], a);     // Sk * Wk
            }
            a = fmaf(a, scale, bias[o]);
            #pragma unroll
            for (int i = 0; i < 16; ++i)
                a = fmaf(vn[i], root[i * 16 + o], a);
            val[o] = a;
        }
        #pragma unroll
        for (int i = 0; i < 4; ++i)
            *(float4*)(out + (size_t)n * 16 + i * 4) =
                make_float4(val[4*i+0], val[4*i+1], val[4*i+2], val[4*i+3]);
    } else {
        #pragma unroll
        for (int o = 0; o < 16; ++o) val[o] = 0.0f;
    }

    // batch-stat reduction: wave butterfly -> LDS -> device atomic
    float ssum[16], ssq[16];
    #pragma unroll
    for (int o = 0; o < 16; ++o) {
        float a = val[o];
        float bsq = a * a;
        #pragma unroll
        for (int m = 1; m < 64; m <<= 1) {
            a += __shfl_xor(a, m, 64);
            bsq += __shfl_xor(bsq, m, 64);
        }
        ssum[o] = a; ssq[o] = bsq;
    }
    int wave = tid >> 6;
    int lane = tid & 63;
    if (lane == 0) {
        #pragma unroll
        for (int o = 0; o < 16; ++o) {
            s_part[wave][o]      = ssum[o];
            s_part[wave][16 + o] = ssq[o];
        }
    }
    __syncthreads();
    if (tid < 32) {
        float t = s_part[0][tid] + s_part[1][tid] +
                  s_part[2][tid] + s_part[3][tid];
        unsafeAtomicAdd(stats + tid, t);
    }
}

// Kernel 3: BatchNorm (batch stats) + LeakyReLU, in place, float4-vectorized.
__global__ __launch_bounds__(256) void final_kernel(
    float* __restrict__ out,
    const float* __restrict__ stats,
    const float* __restrict__ gamma,
    const float* __restrict__ beta)
{
    int idx = blockIdx.x * 256 + threadIdx.x;      // float4 index
    if (idx >= N_NODES * 4) return;
    int o0 = (idx & 3) << 2;
    const float invN = 1.0f / (float)N_NODES;
    float4 x = *((const float4*)out + idx);
    float xs[4] = {x.x, x.y, x.z, x.w};
    float r[4];
    #pragma unroll
    for (int u = 0; u < 4; ++u) {
        int o = o0 + u;
        float mu = stats[o] * invN;
        float var = fmaxf(stats[16 + o] * invN - mu * mu, 0.0f);
        float y = fmaf(gamma[o] * (xs[u] - mu), rsqrtf(var + EPS), beta[o]);
        r[u] = (y >= 0.0f) ? y : SLOPE * y;
    }
    *((float4*)out + idx) = make_float4(r[0], r[1], r[2], r[3]);
}

extern "C" void kernel_launch(void* const* d_in, const int* in_sizes, int n_in,
                              void* d_out, int out_size, void* d_ws, size_t ws_size,
                              hipStream_t stream)
{
    const float* v = (const float*)d_in[0];
    const float* e = (const float*)d_in[1];
    const int* edge_index = (const int*)d_in[2];
    const float* enet_w = (const float*)d_in[3];
    const float* enet_b = (const float*)d_in[4];
    const float* root = (const float*)d_in[5];
    const float* bias = (const float*)d_in[6];
    const float* gamma = (const float*)d_in[7];
    const float* beta = (const float*)d_in[8];
    float* out = (float*)d_out;

    char* ws = (char*)d_ws;
    float4*         Pb    = (float4*)ws;          ws += (size_t)NBUCK * BCAP * 32;
    unsigned short* dl    = (unsigned short*)ws;  ws += (size_t)NBUCK * BCAP * 2;
    int*            bcur  = (int*)ws;             ws += (size_t)NBUCK * 4;
    float*          stats = (float*)ws;

    // zero bcur + stats (contiguous, tiny)
    hipMemsetAsync(bcur, 0, (size_t)NBUCK * 4 + 32 * 4, stream);

    bin_kernel<<<NBINB, 256, 0, stream>>>(e, edge_index, bcur, Pb, dl);
    gather_bucket_kernel<<<NBUCK, 256, 0, stream>>>(
        v, Pb, dl, bcur, enet_w, enet_b, root, bias, out, stats);
    final_kernel<<<(N_NODES * 4 + 255) / 256, 256, 0, stream>>>(
        out, stats, gamma, beta);
}